// Round 7
// baseline (58.052 us; speedup 1.0000x reference)
//
#include <hip/hip_runtime.h>

// TensorFusion: out = relu(relu(fused @ W1 + b1) @ W2 + b2) @ W3 + b3
// fused[b, i*1024+j*32+k'] = z0[b,i]*z1[b,j]*z2[b,k'], z* = [x*, 1]
// B=256, D=31 (+1 bias -> 32), FUSED=32768, H1=1024, H2=256, NCLS=4
//
// K1 design (barrier-free): grid = 8 nt x 32 ks = 256 blocks (1/CU),
// 512 threads = 8 waves. KCHUNK = 1024 k = 32 pairs, i == ks for the whole
// block -> fold z0[b,ks] into the z2 register fragment. Wave w owns the
// private n-strip [nt*128 + w*16, +16) x M=256: W1 goes global->reg->f16
// ->MFMA with a depth-4 register ring (32 outstanding dwords/wave). No W1
// LDS, no ds_write, no barriers in the main loop. Partials f16 [ks][b][h].

typedef _Float16 half8 __attribute__((ext_vector_type(8)));
typedef _Float16 half4 __attribute__((ext_vector_type(4)));
typedef float f32x4 __attribute__((ext_vector_type(4)));

#define KSPLIT 32

// ---------------------------------------------------------------------------
__global__ __launch_bounds__(512, 2) void k1_gemm(
    const float* __restrict__ x0, const float* __restrict__ x1,
    const float* __restrict__ x2, const float* __restrict__ W1,
    _Float16* __restrict__ partial)
{
    __shared__ _Float16 z1L[256 * 36];   // z1[b][j], row stride 36 (bank-spread)
    __shared__ _Float16 x2L[256 * 32];   // z2[b][k']

    const int tid  = threadIdx.x;
    const int nt   = blockIdx.x & 7;
    const int ks   = blockIdx.x >> 3;
    const int lane = tid & 63;
    const int w    = __builtin_amdgcn_readfirstlane(tid >> 6);  // wave 0..7
    const int nl   = lane & 15;
    const int g    = lane >> 4;          // 0..3

    // ---- stage z1, z2 as f16 (read-only afterwards)
    for (int idx = tid; idx < 256 * 32; idx += 512) {
        int b = idx >> 5, j = idx & 31;
        z1L[b * 36 + j] = (_Float16)((j < 31) ? x1[b * 31 + j] : 1.0f);
        x2L[b * 32 + j] = (_Float16)((j < 31) ? x2[b * 31 + j] : 1.0f);
    }
    __syncthreads();

    // ---- A-side register fragments: z2v[ms] = z0[b,ks] * z2[b, g*8+e]
    half8 z2v[16];
#pragma unroll
    for (int ms = 0; ms < 16; ++ms) {
        int b = ms * 16 + nl;
        float v0 = (ks < 31) ? x0[b * 31 + ks] : 1.0f;
        half8 xv = *(const half8*)&x2L[b * 32 + g * 8];
        z2v[ms] = xv * (_Float16)v0;
    }

    // ---- W1 access: wave-uniform base + 32-bit per-lane offset
    const float* gw = W1 + ((size_t)ks << 20) + nt * 128 + w * 16;
    const int vbase = g * 8192 + nl;     // (g*8)*1024 + nl

    // ---- depth-4 register ring prologue (steps 0..3)
    float rx[4][8];
#pragma unroll
    for (int s = 0; s < 4; ++s)
#pragma unroll
        for (int e = 0; e < 8; ++e)
            rx[s][e] = gw[s * 32768 + vbase + e * 1024];

    f32x4 acc[16] = {};
    half4 z1q[16];

    // ---- main loop: 32 steps (j = step), 16 MFMA each, zero barriers
#pragma unroll
    for (int grp = 0; grp < 8; ++grp) {
        const int t0 = grp * 4;
#pragma unroll
        for (int ms = 0; ms < 16; ++ms)
            z1q[ms] = *(const half4*)&z1L[(ms * 16 + nl) * 36 + t0];

#pragma unroll
        for (int TT = 0; TT < 4; ++TT) {
            // consume ring slot (compiler emits counted vmcnt for these 8)
            half8 bh;
#pragma unroll
            for (int e = 0; e < 8; ++e) bh[e] = (_Float16)rx[TT][e];
            // refill slot with step t0+TT+4 (skip on last group)
            if (grp < 7) {
                const int base = (t0 + TT + 4) * 32768 + vbase;
#pragma unroll
                for (int e = 0; e < 8; ++e) rx[TT][e] = gw[base + e * 1024];
            }
            // 16 M-subtiles: a = z2v * z1 scalar, accumulate
#pragma unroll
            for (int ms = 0; ms < 16; ++ms) {
                half8 a = z2v[ms] * z1q[ms][TT];
                acc[ms] = __builtin_amdgcn_mfma_f32_16x16x32_f16(a, bh, acc[ms], 0, 0, 0);
            }
        }
    }

    // ---- epilogue: D col = lane&15 (h), row = g*4+r (b); f16 partials
    _Float16* pout = partial + ((size_t)ks << 18) + nt * 128 + w * 16 + nl;
#pragma unroll
    for (int ms = 0; ms < 16; ++ms)
#pragma unroll
        for (int r = 0; r < 4; ++r)
            pout[(ms * 16 + g * 4 + r) * 1024] = (_Float16)acc[ms][r];
}

// ---------------------------------------------------------------------------
// K2: h1[b][h] = relu(sum_ks partial[ks][b][h] + b1[h])
// ---------------------------------------------------------------------------
__global__ __launch_bounds__(256) void k2_reduce(
    const _Float16* __restrict__ partial, const float* __restrict__ b1,
    float* __restrict__ h1)
{
    int e = blockIdx.x * 256 + threadIdx.x;   // grid 1024 -> 262144
    float s = 0.f;
#pragma unroll
    for (int sp = 0; sp < KSPLIT; ++sp) s += (float)partial[((size_t)sp << 18) + e];
    s += b1[e & 1023];
    h1[e] = fmaxf(s, 0.f);
}

// ---------------------------------------------------------------------------
// K3: layer 2 partials, M=256 K=1024 N=256; Mtile=32 Ntile=64 Ksplit=8
// ---------------------------------------------------------------------------
__global__ __launch_bounds__(256) void k3_layer2(
    const float* __restrict__ h1, const float* __restrict__ W2,
    float* __restrict__ p2)
{
    __shared__ float h1t[32 * 129];
    __shared__ float w2t[128 * 65];
    const int tid = threadIdx.x;
    const int m0 = blockIdx.x * 32, n0 = blockIdx.y * 64, k0 = blockIdx.z * 128;

    for (int idx = tid; idx < 32 * 128; idx += 256) {
        int m = idx >> 7, kk = idx & 127;
        h1t[m * 129 + kk] = h1[(m0 + m) * 1024 + k0 + kk];
    }
    for (int idx = tid; idx < 128 * 64; idx += 256) {
        int kk = idx >> 6, n = idx & 63;
        w2t[kk * 65 + n] = W2[(k0 + kk) * 256 + n0 + n];
    }
    __syncthreads();

    const int tn = tid & 63, tm = tid >> 6;   // tm 0..3
    float acc[8] = {};
    for (int kk = 0; kk < 128; ++kk) {
        float wv = w2t[kk * 65 + tn];
#pragma unroll
        for (int r = 0; r < 8; ++r)
            acc[r] += h1t[(tm * 8 + r) * 129 + kk] * wv;
    }
#pragma unroll
    for (int r = 0; r < 8; ++r)
        p2[blockIdx.z * 65536 + (m0 + tm * 8 + r) * 256 + n0 + tn] = acc[r];
}

// ---------------------------------------------------------------------------
// K4: h2 = relu(sum_s p2[s] + b2); out = h2 @ W3 + b3. One block per sample.
// ---------------------------------------------------------------------------
__global__ __launch_bounds__(256) void k4_final(
    const float* __restrict__ p2, const float* __restrict__ b2,
    const float* __restrict__ W3, const float* __restrict__ b3,
    float* __restrict__ out)
{
    __shared__ float pL[256 * 5];
    const int b = blockIdx.x, n = threadIdx.x;
    float s = 0.f;
#pragma unroll
    for (int sp = 0; sp < 8; ++sp) s += p2[sp * 65536 + b * 256 + n];
    float h2 = fmaxf(s + b2[n], 0.f);
#pragma unroll
    for (int c = 0; c < 4; ++c) pL[n * 5 + c] = h2 * W3[n * 4 + c];
    __syncthreads();

    const int lane = n & 63, w = n >> 6;      // wave w handles class c=w
    float v = pL[lane * 5 + w] + pL[(lane + 64) * 5 + w] +
              pL[(lane + 128) * 5 + w] + pL[(lane + 192) * 5 + w];
#pragma unroll
    for (int off = 32; off > 0; off >>= 1) v += __shfl_down(v, off);
    if (lane == 0) out[b * 4 + w] = v + b3[w];
}

extern "C" void kernel_launch(void* const* d_in, const int* in_sizes, int n_in,
                              void* d_out, int out_size, void* d_ws, size_t ws_size,
                              hipStream_t stream)
{
    (void)in_sizes; (void)n_in; (void)out_size; (void)ws_size;
    const float* x0 = (const float*)d_in[0];
    const float* x1 = (const float*)d_in[1];
    const float* x2 = (const float*)d_in[2];
    const float* W1 = (const float*)d_in[3];
    const float* b1 = (const float*)d_in[4];
    const float* W2 = (const float*)d_in[5];
    const float* b2 = (const float*)d_in[6];
    const float* W3 = (const float*)d_in[7];
    const float* b3 = (const float*)d_in[8];
    float* out = (float*)d_out;

    // ws layout: partial f16 [32][256][1024] = 16.78 MB; h1 f32 1 MB; p2 2 MB
    _Float16* partial = (_Float16*)d_ws;
    float* h1 = (float*)((char*)d_ws + (size_t)KSPLIT * 262144 * 2);
    float* p2 = h1 + 262144;

    k1_gemm  <<<dim3(256),     dim3(512), 0, stream>>>(x0, x1, x2, W1, partial);
    k2_reduce<<<dim3(1024),    dim3(256), 0, stream>>>(partial, b1, h1);
    k3_layer2<<<dim3(8, 4, 8), dim3(256), 0, stream>>>(h1, W2, p2);
    k4_final <<<dim3(256),     dim3(256), 0, stream>>>(p2, b2, W3, b3, out);
}

// Round 8
// 53.633 us; speedup vs baseline: 1.0824x; 1.0824x over previous
//
#include <hip/hip_runtime.h>

// TensorFusion: out = relu(relu(fused @ W1 + b1) @ W2 + b2) @ W3 + b3
// fused[b, i*1024+j*32+k'] = z0[b,i]*z1[b,j]*z2[b,k'], z* = [x*, 1]
// B=256, D=31 (+1 bias -> 32), FUSED=32768, H1=1024, H2=256, NCLS=4
//
// K1: 256 blocks (8 nt x 32 ks) x 1024 thr (16 waves) = 1 block/CU.
// Block tile M=256 x N=128, K-chunk 1024 (i = ks constant -> z0 folded).
// 32 K-steps (j = step). W1 staged to LDS: wave w loads its k-row-pair
// (2w, 2w+1) as float2 (512 B contiguous per wave-instr), packs f16
// k-pairs, ds_write with even-XOR swizzle; compute reads 2x ds_read_b64
// per B-frag at the bank minimum. Double-buffered LDS + depth-2 reg ring,
// one lgkmcnt(0)+s_barrier per step (counted vmcnt via compiler).

typedef _Float16 half8 __attribute__((ext_vector_type(8)));
typedef _Float16 half4 __attribute__((ext_vector_type(4)));
typedef _Float16 half2 __attribute__((ext_vector_type(2)));
typedef float f32x4 __attribute__((ext_vector_type(4)));
typedef float f32x2 __attribute__((ext_vector_type(2)));

#define KSPLIT 32

// ---------------------------------------------------------------------------
__global__ __launch_bounds__(1024, 4) void k1_gemm(
    const float* __restrict__ x0, const float* __restrict__ x1,
    const float* __restrict__ x2, const float* __restrict__ W1,
    _Float16* __restrict__ partial)
{
    __shared__ _Float16 z1L[256 * 36];     // z1[b][j], stride 36
    __shared__ _Float16 tileF[2 * 128 * 32];  // dbuf [n][k] f16, swizzled

    const int tid  = threadIdx.x;
    const int nt   = blockIdx.x & 7;
    const int ks   = blockIdx.x >> 3;
    const int lane = tid & 63;
    const int w    = tid >> 6;          // wave 0..15
    const int nl   = lane & 15;
    const int g    = lane >> 4;         // 0..3
    const int mh   = w & 3;             // M strip: rows [mh*64, +64)
    const int nw   = w >> 2;            // N strip: cols [nw*32, +32)

    // ---- z1 table (f16), stride-36 rows
    for (int idx = tid; idx < 256 * 32; idx += 1024) {
        int b = idx >> 5, j = idx & 31;
        z1L[b * 36 + j] = (_Float16)((j < 31) ? x1[b * 31 + j] : 1.0f);
    }

    // ---- A-side fragments: z2v[ms][e] = z0[b,ks] * z2[b, g*8+e]
    half8 z2v[4];
#pragma unroll
    for (int ms = 0; ms < 4; ++ms) {
        int b = mh * 64 + ms * 16 + nl;
        float v0 = (ks < 31) ? x0[b * 31 + ks] : 1.0f;
#pragma unroll
        for (int e = 0; e < 8; ++e) {
            int kp = g * 8 + e;
            float v2 = (kp < 31) ? x2[b * 31 + kp] : 1.0f;
            z2v[ms][e] = (_Float16)(v0 * v2);
        }
    }

    // ---- staging geometry: wave w <-> k-row pair (2w, 2w+1); lane c = cols 2c,2c+1
    const int c = lane;
    const float* gsrc = W1 + ((size_t)ks * 1024 + 2 * w) * 1024 + nt * 128 + 2 * c;
    const int kpw = w ^ ((c & 7) << 1);          // swizzled dword slot
    const int waddr0 = (2 * c) * 32 + kpw * 2;   // f16 idx, row h=2c
    const int waddr1 = waddr0 + 32;              // row h=2c+1

    // ---- B-frag read offsets (f16 idx), 2x b64 per ns
    int raddr[2][2];
#pragma unroll
    for (int ns = 0; ns < 2; ++ns) {
        int n = nw * 32 + ns * 16 + nl;
        int sw = ((n >> 1) & 7) << 1;
#pragma unroll
        for (int u = 0; u < 2; ++u)
            raddr[ns][u] = n * 32 + ((g * 4 + 2 * u) ^ sw) * 2;
    }

    // ---- prologue: depth-2 reg ring; write step0 -> buf0
    f32x2 rA[2], rB[2];
    rA[0] = *(const f32x2*)gsrc;
    rB[0] = *(const f32x2*)(gsrc + 1024);
    rA[1] = *(const f32x2*)(gsrc + 32768);
    rB[1] = *(const f32x2*)(gsrc + 32768 + 1024);
    {
        half2 w0, w1;
        w0[0] = (_Float16)rA[0][0]; w0[1] = (_Float16)rB[0][0];
        w1[0] = (_Float16)rA[0][1]; w1[1] = (_Float16)rB[0][1];
        *(half2*)&tileF[waddr0] = w0;
        *(half2*)&tileF[waddr1] = w1;
    }
    __syncthreads();

    f32x4 acc[4][2] = {};
    half4 z1q[4];

    // STEP(T_): compute buf[T_&1]; issue loads T_+2 into slot T_&1 (freed
    // last step); cvt+write T_+1 from slot (T_+1)&1 into buf[(T_+1)&1];
    // lgkmcnt(0)+barrier gates next step's reads.
#define STEP(T_, TT, LOADF, WRITEF)                                            \
    {                                                                          \
        if (LOADF) {                                                           \
            const float* gp = gsrc + (size_t)((T_) + 2) * 32768;               \
            rA[(TT) & 1] = *(const f32x2*)gp;                                  \
            rB[(TT) & 1] = *(const f32x2*)(gp + 1024);                         \
        }                                                                      \
        if ((TT) == 0) {                                                       \
            _Pragma("unroll")                                                  \
            for (int ms = 0; ms < 4; ++ms)                                     \
                z1q[ms] = *(const half4*)&z1L[(mh * 64 + ms * 16 + nl) * 36 + t0]; \
        }                                                                      \
        const _Float16* tb = &tileF[((TT) & 1) * 4096];                        \
        half4 lo0 = *(const half4*)&tb[raddr[0][0]];                           \
        half4 hi0 = *(const half4*)&tb[raddr[0][1]];                           \
        half4 lo1 = *(const half4*)&tb[raddr[1][0]];                           \
        half4 hi1 = *(const half4*)&tb[raddr[1][1]];                           \
        half8 bh0 = __builtin_shufflevector(lo0, hi0, 0,1,2,3,4,5,6,7);        \
        half8 bh1 = __builtin_shufflevector(lo1, hi1, 0,1,2,3,4,5,6,7);        \
        _Pragma("unroll")                                                      \
        for (int ms = 0; ms < 4; ++ms) {                                       \
            half8 a = z2v[ms] * z1q[ms][TT];                                   \
            acc[ms][0] = __builtin_amdgcn_mfma_f32_16x16x32_f16(a, bh0, acc[ms][0], 0, 0, 0); \
            acc[ms][1] = __builtin_amdgcn_mfma_f32_16x16x32_f16(a, bh1, acc[ms][1], 0, 0, 0); \
        }                                                                      \
        if (WRITEF) {                                                          \
            half2 w0, w1;                                                      \
            w0[0] = (_Float16)rA[((TT) + 1) & 1][0];                           \
            w0[1] = (_Float16)rB[((TT) + 1) & 1][0];                           \
            w1[0] = (_Float16)rA[((TT) + 1) & 1][1];                           \
            w1[1] = (_Float16)rB[((TT) + 1) & 1][1];                           \
            _Float16* tw = &tileF[(((TT) + 1) & 1) * 4096];                    \
            *(half2*)&tw[waddr0] = w0;                                         \
            *(half2*)&tw[waddr1] = w1;                                         \
        }                                                                      \
        asm volatile("s_waitcnt lgkmcnt(0)\n\ts_barrier" ::: "memory");        \
    }

    for (int grp = 0; grp < 7; ++grp) {
        const int t0 = grp * 4;
        STEP(t0 + 0, 0, 1, 1)
        STEP(t0 + 1, 1, 1, 1)
        STEP(t0 + 2, 2, 1, 1)
        STEP(t0 + 3, 3, 1, 1)
    }
    {
        const int t0 = 28;
        STEP(28, 0, 1, 1)
        STEP(29, 1, 1, 1)
        STEP(30, 2, 0, 1)
        STEP(31, 3, 0, 0)
    }
#undef STEP

    // ---- epilogue: D col = lane&15 (h), row = g*4 + r (b); f16 partials
    _Float16* pbase = partial + ((size_t)ks << 18);
#pragma unroll
    for (int ms = 0; ms < 4; ++ms)
#pragma unroll
        for (int ns = 0; ns < 2; ++ns) {
            int h = nt * 128 + nw * 32 + ns * 16 + nl;
            int b0 = mh * 64 + ms * 16 + g * 4;
#pragma unroll
            for (int r = 0; r < 4; ++r)
                pbase[(b0 + r) * 1024 + h] = (_Float16)acc[ms][ns][r];
        }
}

// ---------------------------------------------------------------------------
// K2: h1[b][h] = relu(sum_ks partial[ks][b][h] + b1[h]); half2 path
// ---------------------------------------------------------------------------
__global__ __launch_bounds__(256) void k2_reduce(
    const _Float16* __restrict__ partial, const float* __restrict__ b1,
    float* __restrict__ h1)
{
    int e2 = blockIdx.x * 256 + threadIdx.x;   // grid 512 -> 131072 pairs
    const half2* pv = (const half2*)partial;
    float s0 = 0.f, s1 = 0.f;
#pragma unroll
    for (int sp = 0; sp < KSPLIT; ++sp) {
        half2 v = pv[(size_t)sp * 131072 + e2];
        s0 += (float)v[0]; s1 += (float)v[1];
    }
    int h = (e2 * 2) & 1023;
    f32x2 o;
    o[0] = fmaxf(s0 + b1[h], 0.f);
    o[1] = fmaxf(s1 + b1[h + 1], 0.f);
    *(f32x2*)&h1[e2 * 2] = o;
}

// ---------------------------------------------------------------------------
// K3: layer 2 partials, M=256 K=1024 N=256; Mtile=32 Ntile=64 Ksplit=8
// ---------------------------------------------------------------------------
__global__ __launch_bounds__(256) void k3_layer2(
    const float* __restrict__ h1, const float* __restrict__ W2,
    float* __restrict__ p2)
{
    __shared__ float h1t[32 * 129];
    __shared__ float w2t[128 * 65];
    const int tid = threadIdx.x;
    const int m0 = blockIdx.x * 32, n0 = blockIdx.y * 64, k0 = blockIdx.z * 128;

    for (int idx = tid; idx < 32 * 128; idx += 256) {
        int m = idx >> 7, kk = idx & 127;
        h1t[m * 129 + kk] = h1[(m0 + m) * 1024 + k0 + kk];
    }
    for (int idx = tid; idx < 128 * 64; idx += 256) {
        int kk = idx >> 6, n = idx & 63;
        w2t[kk * 65 + n] = W2[(k0 + kk) * 256 + n0 + n];
    }
    __syncthreads();

    const int tn = tid & 63, tm = tid >> 6;   // tm 0..3
    float acc[8] = {};
    for (int kk = 0; kk < 128; ++kk) {
        float wv = w2t[kk * 65 + tn];
#pragma unroll
        for (int r = 0; r < 8; ++r)
            acc[r] += h1t[(tm * 8 + r) * 129 + kk] * wv;
    }
#pragma unroll
    for (int r = 0; r < 8; ++r)
        p2[blockIdx.z * 65536 + (m0 + tm * 8 + r) * 256 + n0 + tn] = acc[r];
}

// ---------------------------------------------------------------------------
// K4: h2 = relu(sum_s p2[s] + b2); out = h2 @ W3 + b3. One block per sample.
// ---------------------------------------------------------------------------
__global__ __launch_bounds__(256) void k4_final(
    const float* __restrict__ p2, const float* __restrict__ b2,
    const float* __restrict__ W3, const float* __restrict__ b3,
    float* __restrict__ out)
{
    __shared__ float pL[256 * 5];
    const int b = blockIdx.x, n = threadIdx.x;
    float s = 0.f;
#pragma unroll
    for (int sp = 0; sp < 8; ++sp) s += p2[sp * 65536 + b * 256 + n];
    float h2 = fmaxf(s + b2[n], 0.f);
#pragma unroll
    for (int ccls = 0; ccls < 4; ++ccls) pL[n * 5 + ccls] = h2 * W3[n * 4 + ccls];
    __syncthreads();

    const int lane = n & 63, w = n >> 6;      // wave w handles class c=w
    float v = pL[lane * 5 + w] + pL[(lane + 64) * 5 + w] +
              pL[(lane + 128) * 5 + w] + pL[(lane + 192) * 5 + w];
#pragma unroll
    for (int off = 32; off > 0; off >>= 1) v += __shfl_down(v, off);
    if (lane == 0) out[b * 4 + w] = v + b3[w];
}

extern "C" void kernel_launch(void* const* d_in, const int* in_sizes, int n_in,
                              void* d_out, int out_size, void* d_ws, size_t ws_size,
                              hipStream_t stream)
{
    (void)in_sizes; (void)n_in; (void)out_size; (void)ws_size;
    const float* x0 = (const float*)d_in[0];
    const float* x1 = (const float*)d_in[1];
    const float* x2 = (const float*)d_in[2];
    const float* W1 = (const float*)d_in[3];
    const float* b1 = (const float*)d_in[4];
    const float* W2 = (const float*)d_in[5];
    const float* b2 = (const float*)d_in[6];
    const float* W3 = (const float*)d_in[7];
    const float* b3 = (const float*)d_in[8];
    float* out = (float*)d_out;

    // ws layout: partial f16 [32][256][1024] = 16.78 MB; h1 f32 1 MB; p2 2 MB
    _Float16* partial = (_Float16*)d_ws;
    float* h1 = (float*)((char*)d_ws + (size_t)KSPLIT * 262144 * 2);
    float* p2 = h1 + 262144;

    k1_gemm  <<<dim3(256),     dim3(1024), 0, stream>>>(x0, x1, x2, W1, partial);
    k2_reduce<<<dim3(512),     dim3(256),  0, stream>>>(partial, b1, h1);
    k3_layer2<<<dim3(8, 4, 8), dim3(256),  0, stream>>>(h1, W2, p2);
    k4_final <<<dim3(256),     dim3(256),  0, stream>>>(p2, b2, W3, b3, out);
}